// Round 5
// baseline (297.604 us; speedup 1.0000x reference)
//
#include <hip/hip_runtime.h>
#include <cstdint>

#define B_ 256
#define T_ 512
#define D_ 128
#define U_ 128

typedef _Float16 h2_t __attribute__((ext_vector_type(2)));
typedef _Float16 f16x4 __attribute__((ext_vector_type(4)));
typedef _Float16 f16x8 __attribute__((ext_vector_type(8)));
typedef float f32x4 __attribute__((ext_vector_type(4)));

static __device__ __forceinline__ uint32_t pack2(float a, float b) {
  h2_t h;
  h.x = (_Float16)a;
  h.y = (_Float16)b;
  return __builtin_bit_cast(uint32_t, h);
}
static __device__ __forceinline__ h2_t as_h2(uint32_t u) {
  return __builtin_bit_cast(h2_t, u);
}
static __device__ __forceinline__ float dot2acc(uint32_t a, uint32_t w, float acc) {
#if __has_builtin(__builtin_amdgcn_fdot2)
  return __builtin_amdgcn_fdot2(as_h2(a), as_h2(w), acc, false);
#else
  h2_t ha = as_h2(a), hw = as_h2(w);
  return acc + (float)ha.x * (float)hw.x + (float)ha.y * (float)hw.y;
#endif
}

// ---- raw transcendentals (no div-fixup sequences) --------------------------
static __device__ __forceinline__ float fexp2(float x) {
#if __has_builtin(__builtin_amdgcn_exp2f)
  return __builtin_amdgcn_exp2f(x);
#else
  return __exp2f(x);
#endif
}
static __device__ __forceinline__ float frcp(float x) {
#if __has_builtin(__builtin_amdgcn_rcpf)
  return __builtin_amdgcn_rcpf(x);
#else
  return __frcp_rn(x);
#endif
}
#define LOG2E_ 1.44269504f
static __device__ __forceinline__ float sigm(float v) {
  return frcp(1.0f + fexp2(-LOG2E_ * v));
}
static __device__ __forceinline__ float tanh_(float v) {
  float r = frcp(1.0f + fexp2(-2.0f * LOG2E_ * v));
  return __builtin_fmaf(2.0f, r, -1.0f);
}

// ---------------- kernel 0: transpose W to f16 [col][k] ---------------------
__global__ __launch_bounds__(256) void wt_kernel(const float* __restrict__ W,
                                                 _Float16* __restrict__ Wtx,
                                                 _Float16* __restrict__ Wth) {
  int id = blockIdx.x * 256 + threadIdx.x;  // 131072 = 512 cols x 256 k
  int col = id >> 8, k = id & 255;
  _Float16 v = (_Float16)W[(size_t)k * 512 + col];
  if (k < 128) Wtx[col * 128 + k] = v;
  else Wth[col * 128 + (k - 128)] = v;
}

// ---------------- kernel A: gx2 = x @ Wx + bias' (f16, gate-interleaved) ----
// gx2[row][u][g]: row = b*T+t, u = unit, g = gate (i,j,f,o). forget bias folded.
__global__ __launch_bounds__(256, 2) void gx_kernel(const float* __restrict__ x,
                                                    const _Float16* __restrict__ Wt,
                                                    const float* __restrict__ bias,
                                                    _Float16* __restrict__ gx) {
  __shared__ __align__(16) _Float16 As[64 * 136];
  const int tid = threadIdx.x;
  const int w = tid >> 6, l = tid & 63;
  const size_t rowBase = (size_t)blockIdx.x * 64;

  const float4* xs = reinterpret_cast<const float4*>(x + rowBase * 128);
#pragma unroll
  for (int n = 0; n < 8; ++n) {
    int idx4 = tid + 256 * n;
    float4 v = xs[idx4];
    int f = idx4 * 4;
    int r = f >> 7, cc = f & 127;
    f16x4 p;
    p.x = (_Float16)v.x; p.y = (_Float16)v.y;
    p.z = (_Float16)v.z; p.w = (_Float16)v.w;
    *reinterpret_cast<f16x4*>(&As[r * 136 + cc]) = p;
  }
  __syncthreads();

  f16x8 af[4][4];
#pragma unroll
  for (int rt = 0; rt < 4; ++rt)
#pragma unroll
    for (int kk = 0; kk < 4; ++kk)
      af[rt][kk] = *reinterpret_cast<const f16x8*>(
          &As[(16 * rt + (l & 15)) * 136 + 32 * kk + 8 * (l >> 4)]);

  const int colBase = 128 * w;
#pragma unroll 1
  for (int ct = 0; ct < 8; ++ct) {
    const int col = colBase + 16 * ct + (l & 15);
    const float bb = bias[col] + ((col >= 256 && col < 384) ? 1.0f : 0.0f);
    f32x4 acc[4];
#pragma unroll
    for (int rt = 0; rt < 4; ++rt) acc[rt] = (f32x4){0.f, 0.f, 0.f, 0.f};
    const _Float16* wtc = Wt + (size_t)col * 128 + 8 * (l >> 4);
#pragma unroll
    for (int kk = 0; kk < 4; ++kk) {
      f16x8 bf = *reinterpret_cast<const f16x8*>(wtc + 32 * kk);
#pragma unroll
      for (int rt = 0; rt < 4; ++rt)
        acc[rt] = __builtin_amdgcn_mfma_f32_16x16x32_f16(af[rt][kk], bf, acc[rt], 0, 0, 0);
    }
    const int u = col & 127, g = col >> 7;
#pragma unroll
    for (int rt = 0; rt < 4; ++rt) {
      size_t row = rowBase + 16 * rt + 4 * (l >> 4);
#pragma unroll
      for (int j = 0; j < 4; ++j)
        gx[(row + j) * 512 + u * 4 + g] = (_Float16)(acc[rt][j] + bb);
    }
  }
}

// ---------------- kernel B: MFMA recurrence ---------------------------------
// Wave w owns cols {128g + 16w + (l&15)}. All MFMA rows identical -> every
// lane holds gate g of unit u in acc[0]. In-lane pointwise update, 1 barrier.
// launch_bounds(512,1): allow up to 256 VGPR so Wth frags stay resident.
__global__ __launch_bounds__(512, 1) void rec_kernel(
    const _Float16* __restrict__ Wth,  // [512 cols][128 k] f16
    const uint16_t* __restrict__ gx2,  // [B*T][128][4] f16 bits
    float* __restrict__ out) {
  __shared__ __align__(16) _Float16 hbuf[2][128];
  const int tid = threadIdx.x;
  const int b = blockIdx.x;
  const int w = tid >> 6, l = tid & 63;
  const int lq = l >> 4;
  const int u = 16 * w + (l & 15);
  const bool wr = (lq == 0);

  // B fragments: bw[g][kk] = Wth[col=128g+u][k=32kk+8lq .. +8]
  f16x8 bw[4][4];
#pragma unroll
  for (int g = 0; g < 4; ++g) {
    const _Float16* wc = Wth + (size_t)(128 * g + u) * 128 + 8 * lq;
#pragma unroll
    for (int kk = 0; kk < 4; ++kk)
      bw[g][kk] = *reinterpret_cast<const f16x8*>(wc + 32 * kk);
  }

  const uint16_t* gxb = gx2 + (size_t)b * T_ * 512 + 4 * u;
  float* ob = out + (size_t)b * T_ * U_ + u;

  if (tid < 64) reinterpret_cast<uint32_t*>(&hbuf[0][0])[tid] = 0u;  // h = 0

  const f32x4 Z = {0.f, 0.f, 0.f, 0.f};
  float cst = 0.0f;

#define GXLD(idx) \
  (*reinterpret_cast<const f16x4*>(gxb + (size_t)((idx) < T_ ? (idx) : (T_ - 1)) * 512))

  f16x4 gp0 = GXLD(0), gp1 = GXLD(1), gp2 = GXLD(2), gp3 = GXLD(3);
  __syncthreads();

  // 2||2 kk accumulation: two independent depth-2 MFMA chains per gate.
#define STEP(tt, p, gv)                                                           \
  {                                                                               \
    const _Float16* hb = &hbuf[p][0];                                             \
    f16x8 a0 = *reinterpret_cast<const f16x8*>(hb + 8 * lq);                      \
    f16x8 a1 = *reinterpret_cast<const f16x8*>(hb + 32 + 8 * lq);                 \
    f16x8 a2 = *reinterpret_cast<const f16x8*>(hb + 64 + 8 * lq);                 \
    f16x8 a3 = *reinterpret_cast<const f16x8*>(hb + 96 + 8 * lq);                 \
    f32x4 cA[4], cB[4];                                                           \
    _Pragma("unroll") for (int g = 0; g < 4; ++g)                                 \
        cA[g] = __builtin_amdgcn_mfma_f32_16x16x32_f16(a0, bw[g][0], Z, 0, 0, 0); \
    _Pragma("unroll") for (int g = 0; g < 4; ++g)                                 \
        cB[g] = __builtin_amdgcn_mfma_f32_16x16x32_f16(a2, bw[g][2], Z, 0, 0, 0); \
    _Pragma("unroll") for (int g = 0; g < 4; ++g)                                 \
        cA[g] = __builtin_amdgcn_mfma_f32_16x16x32_f16(a1, bw[g][1], cA[g], 0, 0, 0); \
    _Pragma("unroll") for (int g = 0; g < 4; ++g)                                 \
        cB[g] = __builtin_amdgcn_mfma_f32_16x16x32_f16(a3, bw[g][3], cB[g], 0, 0, 0); \
    const float gi = (cA[0][0] + cB[0][0]) + (float)(gv).x;                       \
    const float gj = (cA[1][0] + cB[1][0]) + (float)(gv).y;                       \
    const float gf = (cA[2][0] + cB[2][0]) + (float)(gv).z;                       \
    const float go = (cA[3][0] + cB[3][0]) + (float)(gv).w;                       \
    cst = cst * sigm(gf) + sigm(gi) * tanh_(gj);                                  \
    const float hh = tanh_(cst) * sigm(go);                                       \
    if (wr) {                                                                     \
      hbuf[(p) ^ 1][u] = (_Float16)hh;                                            \
      ob[(size_t)(tt) * U_] = hh;                                                 \
    }                                                                             \
    __syncthreads();                                                              \
  }

#pragma unroll 1
  for (int t = 0; t < T_; t += 4) {
    // keep the 16 weight fragments live in registers across the loop body;
    // prevents the allocator from sinking their loads into the loop.
#pragma unroll
    for (int g = 0; g < 4; ++g) {
      asm volatile("" ::"v"(bw[g][0]), "v"(bw[g][1]), "v"(bw[g][2]), "v"(bw[g][3]));
    }
    STEP(t + 0, 0, gp0)
    gp0 = GXLD(t + 4);
    STEP(t + 1, 1, gp1)
    gp1 = GXLD(t + 5);
    STEP(t + 2, 0, gp2)
    gp2 = GXLD(t + 6);
    STEP(t + 3, 1, gp3)
    gp3 = GXLD(t + 7);
  }
#undef STEP
#undef GXLD
}

// ---------------- round-1 fallback (ws too small) ---------------------------
__global__ __launch_bounds__(512, 2) void lstm_fused_kernel(
    const float* __restrict__ x, const float* __restrict__ W,
    const float* __restrict__ bias, float* __restrict__ out) {
  __shared__ __align__(16) uint32_t a_lds[2][128];
  __shared__ float g_lds[512];
  const int tid = threadIdx.x;
  const int b = blockIdx.x;
  uint32_t wreg[128];
#pragma unroll
  for (int q4 = 0; q4 < 32; ++q4) {
    float f[8];
#pragma unroll
    for (int r = 0; r < 8; ++r) f[r] = W[(q4 * 8 + r) * 512 + tid];
#pragma unroll
    for (int rr = 0; rr < 4; ++rr)
      wreg[q4 * 4 + rr] = pack2(f[2 * rr], f[2 * rr + 1]);
  }
  const float bjv = bias[tid];
  const float* xb = x + (size_t)b * (T_ * D_);
  float* ob = out + (size_t)b * (T_ * U_);
  if (tid < 32) {
    float4 x4 = reinterpret_cast<const float4*>(xb)[tid];
    reinterpret_cast<uint2*>(&a_lds[0][0])[tid] =
        make_uint2(pack2(x4.x, x4.y), pack2(x4.z, x4.w));
  }
  if (tid >= 64 && tid < 128) a_lds[0][tid] = 0u;
  __syncthreads();
  float c = 0.0f;
  int p = 0;
  for (int t = 0; t < T_; ++t) {
    float4 xp;
    const bool pf = (tid < 32) && (t + 1 < T_);
    if (pf) xp = reinterpret_cast<const float4*>(xb + (t + 1) * D_)[tid];
    const uint4* av = reinterpret_cast<const uint4*>(&a_lds[p][0]);
    float a0 = bjv, a1 = 0.0f, a2 = 0.0f, a3 = 0.0f;
#pragma unroll
    for (int q = 0; q < 32; ++q) {
      uint4 a4 = av[q];
      a0 = dot2acc(a4.x, wreg[4 * q + 0], a0);
      a1 = dot2acc(a4.y, wreg[4 * q + 1], a1);
      a2 = dot2acc(a4.z, wreg[4 * q + 2], a2);
      a3 = dot2acc(a4.w, wreg[4 * q + 3], a3);
    }
    g_lds[tid] = (a0 + a1) + (a2 + a3);
    __syncthreads();
    if (tid < 128) {
      const float gi = g_lds[tid];
      const float gj = g_lds[128 + tid];
      const float gf = g_lds[256 + tid];
      const float go = g_lds[384 + tid];
      c = c * sigm(gf + 1.0f) + sigm(gi) * tanh_(gj);
      const float h = tanh_(c) * sigm(go);
      ob[t * U_ + tid] = h;
      reinterpret_cast<_Float16*>(&a_lds[p ^ 1][64])[tid] = (_Float16)h;
    }
    if (pf) {
      reinterpret_cast<uint2*>(&a_lds[p ^ 1][0])[tid] =
          make_uint2(pack2(xp.x, xp.y), pack2(xp.z, xp.w));
    }
    __syncthreads();
    p ^= 1;
  }
}

extern "C" void kernel_launch(void* const* d_in, const int* in_sizes, int n_in,
                              void* d_out, int out_size, void* d_ws, size_t ws_size,
                              hipStream_t stream) {
  (void)in_sizes; (void)n_in; (void)out_size;
  const float* x = (const float*)d_in[0];
  const float* W = (const float*)d_in[1];
  const float* b = (const float*)d_in[2];
  float* out = (float*)d_out;

  const size_t WTX_BYTES = (size_t)512 * 128 * 2;
  const size_t WTH_BYTES = (size_t)512 * 128 * 2;
  const size_t GX_BYTES = (size_t)B_ * T_ * 512 * 2;
  if (ws_size >= WTX_BYTES + WTH_BYTES + GX_BYTES) {
    _Float16* wtx = (_Float16*)d_ws;
    _Float16* wth = (_Float16*)((char*)d_ws + WTX_BYTES);
    _Float16* gxp = (_Float16*)((char*)d_ws + WTX_BYTES + WTH_BYTES);
    wt_kernel<<<512, 256, 0, stream>>>(W, wtx, wth);
    gx_kernel<<<2048, 256, 0, stream>>>(x, wtx, b, gxp);
    rec_kernel<<<256, 512, 0, stream>>>(wth, (const uint16_t*)gxp, out);
  } else {
    lstm_fused_kernel<<<256, 512, 0, stream>>>(x, W, b, out);
  }
}